// Round 15
// baseline (15378.046 us; speedup 1.0000x reference)
//
#include <hip/hip_runtime.h>
#include <math.h>

// Clean-room fused implementation. B=64, I=2048, H=2048, T=128.
// One wave (64 lanes) per h; lane = batch b. No LDS, no workspace.
// Numerics contract (jax-on-CPU / XLA:CPU recompute of the reference):
//  * weighted: dot_general -> Eigen gebp contraction. K blocked by the
//    GeneralBlockPanelKernel heuristic: kc = min((l1-k_sub)/k_div, 320)
//    -> kc=320 (cap binds; multiple of k_peeling=8). Per C element:
//    ascending-k FMA chain within each 320-panel (vfmadd, one register
//    accumulator), panels combined by UNFUSED adds into C (beta=0 first).
//    2048 = 6x320 + 128.
//  * scan: XLA elemental emitter, separate fmul/fadd per HLO op -> f32
//    UNFUSED mul/add; reduce-mean over 64 exact -> ballot/popcount * 1/64.
//  * exp: scalar f32 exp -> libm expf (correctly rounded); built as
//    (float)exp((double)x) of the f32-rounded quotient (weak python float
//    / f32 -> f32 division).

#define PANEL 320   // Eigen gebp kc (heuristic 320-cap, k_peeling=8)

__global__ __launch_bounds__(64) void snn_fused_kernel(
    const float* __restrict__ spikes,     // [64][2048][128]
    const float* __restrict__ weight,     // [2048][2048]
    const float* __restrict__ strength,   // [2048][2048]
    const float* __restrict__ threshold,  // [2048]
    const float* __restrict__ p_tau_mem,
    const float* __restrict__ p_tau_syn,
    const float* __restrict__ p_target,
    const float* __restrict__ p_lr,
    float* __restrict__ out)              // [64][2048][128]
{
    const int h = blockIdx.x;     // one wave per h
    const int b = threadIdx.x;    // lane = batch

    // correctly-rounded f32 exp of f32-rounded quotient
    const float a_mem  = (float)exp((double)__fdiv_rn(-0.001f, p_tau_mem[0]));
    const float a_syn  = (float)exp((double)__fdiv_rn(-0.001f, p_tau_syn[0]));
    const float target = p_target[0];
    const float lr     = p_lr[0];

    float i_syn = 0.0f, v_mem = 0.0f;
    float thr = threshold[h];
    float fre = 0.0f;

    const float* sb = spikes + (size_t)b * 262144;   // [i][t] slab for batch b

    for (int tc = 0; tc < 128; tc += 16) {
        // ---- weighted[tc..tc+15] for (b,h): Eigen kc=320 panel-blocked ----
        float tot[16];
#pragma unroll
        for (int u = 0; u < 16; u++) tot[u] = 0.0f;

        const float* sp = sb + tc;
        for (int p0 = 0; p0 < 2048; p0 += PANEL) {
            const int pend = (p0 + PANEL < 2048) ? (p0 + PANEL) : 2048;
            float acc[16];
#pragma unroll
            for (int u = 0; u < 16; u++) acc[u] = 0.0f;

            for (int i = p0; i < pend; i++) {
                const float w = __fmul_rn(weight[(size_t)i * 2048 + h],
                                          strength[(size_t)i * 2048 + h]);
                const float4 s0 = *(const float4*)(sp + (size_t)i * 128);
                const float4 s1 = *(const float4*)(sp + (size_t)i * 128 + 4);
                const float4 s2 = *(const float4*)(sp + (size_t)i * 128 + 8);
                const float4 s3 = *(const float4*)(sp + (size_t)i * 128 + 12);
                acc[0]  = __builtin_fmaf(s0.x, w, acc[0]);
                acc[1]  = __builtin_fmaf(s0.y, w, acc[1]);
                acc[2]  = __builtin_fmaf(s0.z, w, acc[2]);
                acc[3]  = __builtin_fmaf(s0.w, w, acc[3]);
                acc[4]  = __builtin_fmaf(s1.x, w, acc[4]);
                acc[5]  = __builtin_fmaf(s1.y, w, acc[5]);
                acc[6]  = __builtin_fmaf(s1.z, w, acc[6]);
                acc[7]  = __builtin_fmaf(s1.w, w, acc[7]);
                acc[8]  = __builtin_fmaf(s2.x, w, acc[8]);
                acc[9]  = __builtin_fmaf(s2.y, w, acc[9]);
                acc[10] = __builtin_fmaf(s2.z, w, acc[10]);
                acc[11] = __builtin_fmaf(s2.w, w, acc[11]);
                acc[12] = __builtin_fmaf(s3.x, w, acc[12]);
                acc[13] = __builtin_fmaf(s3.y, w, acc[13]);
                acc[14] = __builtin_fmaf(s3.z, w, acc[14]);
                acc[15] = __builtin_fmaf(s3.w, w, acc[15]);
            }
            // C += panel sum (unfused f32 add; beta=0 -> 0+p0 exact)
#pragma unroll
            for (int u = 0; u < 16; u++) tot[u] = __fadd_rn(tot[u], acc[u]);
        }

        // ---- scan these 16 steps (t ascending), f32 unfused ----
        float res[16];
#pragma unroll
        for (int u = 0; u < 16; u++) {
            const float wv = tot[u];
            i_syn = __fadd_rn(__fmul_rn(a_syn, i_syn), wv);
            v_mem = __fadd_rn(__fmul_rn(a_mem, v_mem), i_syn);
            const bool spk = (v_mem >= thr);
            const unsigned long long mask = __ballot(spk);
            if (spk) v_mem = __fsub_rn(v_mem, thr);   // v - 1*thr exact
            const float rate = __fmul_rn((float)__popcll(mask), 0.015625f);
            fre = __fadd_rn(__fmul_rn(0.99f, fre), __fmul_rn(0.01f, rate));
            thr = __fadd_rn(thr, __fmul_rn(lr, __fsub_rn(fre, target)));
            res[u] = spk ? 1.0f : 0.0f;
        }

        float* ob = out + ((size_t)b * 2048 + h) * 128 + tc;
        *(float4*)(ob + 0)  = make_float4(res[0],  res[1],  res[2],  res[3]);
        *(float4*)(ob + 4)  = make_float4(res[4],  res[5],  res[6],  res[7]);
        *(float4*)(ob + 8)  = make_float4(res[8],  res[9],  res[10], res[11]);
        *(float4*)(ob + 12) = make_float4(res[12], res[13], res[14], res[15]);
    }
}

extern "C" void kernel_launch(void* const* d_in, const int* in_sizes, int n_in,
                              void* d_out, int out_size, void* d_ws, size_t ws_size,
                              hipStream_t stream) {
    const float* spikes    = (const float*)d_in[0];
    const float* weight    = (const float*)d_in[1];
    const float* strength  = (const float*)d_in[2];
    const float* threshold = (const float*)d_in[3];
    const float* tau_mem   = (const float*)d_in[4];
    const float* tau_syn   = (const float*)d_in[5];
    const float* target    = (const float*)d_in[6];
    const float* lr        = (const float*)d_in[7];
    float* out = (float*)d_out;

    snn_fused_kernel<<<2048, 64, 0, stream>>>(
        spikes, weight, strength, threshold,
        tau_mem, tau_syn, target, lr, out);
}

// Round 16
// 1015.090 us; speedup vs baseline: 15.1494x; 15.1494x over previous
//
#include <hip/hip_runtime.h>
#include <math.h>

// B=64, I=K=2048, H=N=2048, T=128.  m = b*128 + t (M=8192).
// Numerics contract (VALIDATED GREEN in round 15 — XLA:CPU recompute):
//  * weighted: Eigen gebp, kc=320 K-panels. Per C element: ascending-k FMA
//    chain within each 320-panel (register accumulator), panels combined by
//    UNFUSED f32 adds into the total (beta=0 first). 2048 = 6x320 + 128.
//  * scan: f32 state, UNFUSED mul/add; batch mean exact via ballot/popcount.
//  * exp: correctly-rounded f32 expf via (float)exp((double)x) of the
//    f32-rounded quotient.
// This round ports those exact numerics into the tiled 2-kernel pipeline:
// KT=32 k-tiles; panel fold (tot = fadd(tot, acc); acc = 0) after tiles
// 9,19,29,39,49,59 (i=320j) and after tile 63 (the 128-term tail panel).

#define KT 32

__global__ __launch_bounds__(256) void gemm_kernel(
    const float* __restrict__ spikes,    // [B][I][T] = [64][2048][128]
    const float* __restrict__ weight,    // [I][H]
    const float* __restrict__ strength,  // [I][H]
    float* __restrict__ Ct,              // [Hc][M] chunk-local
    int h_base)
{
    __shared__ __align__(16) float A_lds[KT][132];
    __shared__ __align__(16) float W_lds[KT][132];

    const int tid = threadIdx.x;
    const int bx  = blockIdx.x;          // h-tile within chunk
    const int by  = blockIdx.y;          // batch b
    const int m0  = by * 128;
    const int h0l = bx * 128;
    const int h0g = h_base + h0l;
    const int tx  = tid & 15;
    const int ty  = tid >> 4;
    const int r   = tid >> 5;
    const int c   = tid & 31;

    float acc[8][8];   // current 320-panel accumulator (ascending-k FMA chain)
    float tot[8][8];   // running unfused panel total (Eigen C accumulate)
#pragma unroll
    for (int i = 0; i < 8; i++)
#pragma unroll
        for (int j = 0; j < 8; j++) { acc[i][j] = 0.0f; tot[i][j] = 0.0f; }

    const float* a_base = spikes + (size_t)by * 262144;  // b * I * T

    for (int kt = 0; kt < 64; kt++) {
        const int k0 = kt * KT;
#pragma unroll
        for (int p = 0; p < 4; p++) {
            const int row = r + 8 * p;
            float4 av = *(const float4*)&a_base[(size_t)(k0 + row) * 128 + 4 * c];
            A_lds[row][4 * c + 0] = av.x;
            A_lds[row][4 * c + 1] = av.y;
            A_lds[row][4 * c + 2] = av.z;
            A_lds[row][4 * c + 3] = av.w;
            float4 wv = *(const float4*)&weight[(size_t)(k0 + row) * 2048 + h0g + 4 * c];
            float4 sv = *(const float4*)&strength[(size_t)(k0 + row) * 2048 + h0g + 4 * c];
            // w_eff = weight*strength, f32 rounding (exact here: strength==1)
            W_lds[row][4 * c + 0] = __fmul_rn(wv.x, sv.x);
            W_lds[row][4 * c + 1] = __fmul_rn(wv.y, sv.y);
            W_lds[row][4 * c + 2] = __fmul_rn(wv.z, sv.z);
            W_lds[row][4 * c + 3] = __fmul_rn(wv.w, sv.w);
        }
        __syncthreads();

        // ascending-k FMA chain into the panel accumulator
#pragma unroll 4
        for (int k = 0; k < KT; k++) {
            float4 a0 = *(const float4*)&A_lds[k][4 * ty];
            float4 a1 = *(const float4*)&A_lds[k][4 * ty + 64];
            float4 b0 = *(const float4*)&W_lds[k][4 * tx];
            float4 b1 = *(const float4*)&W_lds[k][4 * tx + 64];
            float a[8] = {a0.x, a0.y, a0.z, a0.w, a1.x, a1.y, a1.z, a1.w};
            float b[8] = {b0.x, b0.y, b0.z, b0.w, b1.x, b1.y, b1.z, b1.w};
#pragma unroll
            for (int i = 0; i < 8; i++)
#pragma unroll
                for (int j = 0; j < 8; j++)
                    acc[i][j] = __builtin_fmaf(a[i], b[j], acc[i][j]);
        }
        __syncthreads();

        // Eigen kc=320 panel boundary: unfused fold into total, reset chain
        if (((kt + 1) % 10 == 0) || (kt == 63)) {
#pragma unroll
            for (int i = 0; i < 8; i++)
#pragma unroll
                for (int j = 0; j < 8; j++) {
                    tot[i][j] = __fadd_rn(tot[i][j], acc[i][j]);
                    acc[i][j] = 0.0f;
                }
        }
    }

#pragma unroll
    for (int j = 0; j < 8; j++) {
        const int hl = h0l + 4 * tx + (j & 3) + ((j >> 2) << 6);
        float4 v0 = make_float4(tot[0][j], tot[1][j], tot[2][j], tot[3][j]);
        float4 v1 = make_float4(tot[4][j], tot[5][j], tot[6][j], tot[7][j]);
        *(float4*)&Ct[(size_t)hl * 8192 + m0 + 4 * ty]      = v0;
        *(float4*)&Ct[(size_t)hl * 8192 + m0 + 4 * ty + 64] = v1;
    }
}

// One wave (64 lanes) per h; lane = batch b. Scan state f32, unfused.
// Batch-mean via ballot/popcount (exact). Validated numerics (R15).
__global__ __launch_bounds__(256) void scan_kernel(
    const float* __restrict__ Wt,          // [Hc][B][T] f32 chunk-local
    const float* __restrict__ threshold,   // [H] f32 global
    const float* __restrict__ p_tau_mem,
    const float* __restrict__ p_tau_syn,
    const float* __restrict__ p_target,
    const float* __restrict__ p_lr,
    float* __restrict__ out,               // [B][H][T] f32 global
    int h_base)
{
    __shared__ float S[4 * 64 * 17];
    __shared__ unsigned int Bits[4][64][4];

    const int tid  = threadIdx.x;
    const int w    = tid >> 6;
    const int lane = tid & 63;            // batch b
    const int hl   = blockIdx.x * 4 + w;  // chunk-local h

    const float tau_mem = p_tau_mem[0];
    const float tau_syn = p_tau_syn[0];
    const float target  = p_target[0];
    const float lr      = p_lr[0];
    // correctly-rounded f32 exp of f32-rounded quotient (libm expf)
    const float a_mem = (float)exp((double)__fdiv_rn(-0.001f, tau_mem));
    const float a_syn = (float)exp((double)__fdiv_rn(-0.001f, tau_syn));

    float i_syn = 0.0f, v_mem = 0.0f;
    float thr = threshold[h_base + hl];
    float fre = 0.0f;
    unsigned int bits[4] = {0u, 0u, 0u, 0u};

    const int st4 = tid & 3;
    const int sb  = (tid >> 2) & 63;

    for (int tc = 0; tc < 128; tc += 16) {
        __syncthreads();
#pragma unroll
        for (int hh = 0; hh < 4; hh++) {
            const int hg = blockIdx.x * 4 + hh;
            float4 v = *(const float4*)&Wt[(size_t)hg * 8192 + sb * 128 + tc + 4 * st4];
            float* row = &S[(hh * 64 + sb) * 17];
            row[4 * st4 + 0] = v.x;
            row[4 * st4 + 1] = v.y;
            row[4 * st4 + 2] = v.z;
            row[4 * st4 + 3] = v.w;
        }
        __syncthreads();

        const float* row = &S[(w * 64 + lane) * 17];
#pragma unroll
        for (int tt = 0; tt < 16; tt++) {
            const int t = tc + tt;
            const float wv = row[tt];
            i_syn = __fadd_rn(__fmul_rn(a_syn, i_syn), wv);
            v_mem = __fadd_rn(__fmul_rn(a_mem, v_mem), i_syn);
            const bool sp = (v_mem >= thr);
            const unsigned long long mask = __ballot(sp);
            if (sp) v_mem = __fsub_rn(v_mem, thr);   // v - 1*thr exact
            const int cnt = __popcll(mask);
            const float rate = __fmul_rn((float)cnt, 0.015625f);  // exact /64
            fre = __fadd_rn(__fmul_rn(0.99f, fre), __fmul_rn(0.01f, rate));
            thr = __fadd_rn(thr, __fmul_rn(lr, __fsub_rn(fre, target)));
            if (sp) bits[t >> 5] |= (1u << (t & 31));
        }
    }

    __syncthreads();
    Bits[w][lane][0] = bits[0];
    Bits[w][lane][1] = bits[1];
    Bits[w][lane][2] = bits[2];
    Bits[w][lane][3] = bits[3];
    __syncthreads();

    for (int b = 0; b < 64; b++) {
        const unsigned int word = Bits[w][b][lane >> 4];
        float2 v;
        v.x = ((word >> ((2 * lane) & 31)) & 1u) ? 1.0f : 0.0f;
        v.y = ((word >> ((2 * lane + 1) & 31)) & 1u) ? 1.0f : 0.0f;
        *(float2*)&out[((size_t)b * 2048 + h_base + hl) * 128 + 2 * lane] = v;
    }
}

extern "C" void kernel_launch(void* const* d_in, const int* in_sizes, int n_in,
                              void* d_out, int out_size, void* d_ws, size_t ws_size,
                              hipStream_t stream) {
    const float* spikes    = (const float*)d_in[0];
    const float* weight    = (const float*)d_in[1];
    const float* strength  = (const float*)d_in[2];
    const float* threshold = (const float*)d_in[3];
    const float* tau_mem   = (const float*)d_in[4];
    const float* tau_syn   = (const float*)d_in[5];
    const float* target    = (const float*)d_in[6];
    const float* lr        = (const float*)d_in[7];

    float* Wt  = (float*)d_ws;
    float* out = (float*)d_out;

    // Chunk H so the f32 Wt intermediate fits in ws_size.
    int Hc = 2048;
    while (Hc > 128 && (size_t)Hc * 8192ull * 4ull > ws_size) Hc >>= 1;

    for (int hb = 0; hb < 2048; hb += Hc) {
        gemm_kernel<<<dim3(Hc / 128, 64), 256, 0, stream>>>(
            spikes, weight, strength, Wt, hb);
        scan_kernel<<<Hc / 4, 256, 0, stream>>>(
            Wt, threshold, tau_mem, tau_syn, target, lr, out, hb);
    }
}